// Round 1
// baseline (769.353 us; speedup 1.0000x reference)
//
#include <hip/hip_runtime.h>

#define D 128
#define TILE 64
#define EPS 1e-10f

// ---------------------------------------------------------------------------
// K1: row_ptr[b] = first index i with node2graph[i] >= b (node2graph sorted)
// ---------------------------------------------------------------------------
__global__ void rowptr_kernel(const int* __restrict__ n2g, int N_, int B_,
                              int* __restrict__ row_ptr) {
    int b = blockIdx.x * 256 + threadIdx.x;
    if (b > B_) return;
    if (b == B_) { row_ptr[b] = N_; return; }
    int lo = 0, hi = N_;
    while (lo < hi) {
        int mid = (lo + hi) >> 1;
        if (n2g[mid] < b) lo = mid + 1; else hi = mid;
    }
    row_ptr[b] = lo;
}

// ---------------------------------------------------------------------------
// K2: b_sum = b_ih + b_hh; step-1 constants h1, c1 (h=c=q_star=0 at step 1)
// gate order (PyTorch): i, f, g, o at j = [0:128),[128:256),[256:384),[384:512)
// ---------------------------------------------------------------------------
__global__ void init_consts_kernel(const float* __restrict__ b_ih,
                                   const float* __restrict__ b_hh,
                                   float* __restrict__ b_sum,
                                   float* __restrict__ c1,
                                   float* __restrict__ h1) {
    int t = threadIdx.x;  // 512 threads, 1 block
    __shared__ float bs[512];
    float v = b_ih[t] + b_hh[t];
    b_sum[t] = v;
    bs[t] = v;
    __syncthreads();
    if (t < D) {
        float ig = 1.f / (1.f + __expf(-bs[t]));
        float gg = tanhf(bs[256 + t]);
        float c  = ig * gg;                       // f*c0 = 0
        float og = 1.f / (1.f + __expf(-bs[384 + t]));
        c1[t] = c;
        h1[t] = og * tanhf(c);
    }
}

// ---------------------------------------------------------------------------
// K3: W1[j][k] = w_ih[j][k] + w_hh[j][k]  (fold hidden weights into input half)
//     const2[j] = b_sum[j] + sum_k h1[k] * W1[j][k]   (step-2 gate constant)
// grid: 512 blocks (one per j), 128 threads
// ---------------------------------------------------------------------------
__global__ void init_w1_kernel(const float* __restrict__ w_ih,
                               const float* __restrict__ w_hh,
                               const float* __restrict__ b_sum,
                               const float* __restrict__ h1,
                               float* __restrict__ W1,
                               float* __restrict__ const2) {
    int j = blockIdx.x, k = threadIdx.x;
    float w = w_ih[j * 256 + k] + w_hh[j * 128 + k];
    W1[j * 128 + k] = w;
    __shared__ float red[128];
    red[k] = w * h1[k];
    __syncthreads();
    for (int s = 64; s > 0; s >>= 1) {
        if (k < s) red[k] += red[k + s];
        __syncthreads();
    }
    if (k == 0) const2[j] = b_sum[j] + red[0];
}

// ---------------------------------------------------------------------------
// K4: tiled GEMM: gates[b][j] = base[j] + A1[b]·Wa[j] (+ A2[b]·Wb[j])
// K per phase is fixed 128. Wa/Wb given as (ptr,row_stride) so W2 can live
// inside w_ih (offset 128, stride 256) without a copy.
// ---------------------------------------------------------------------------
#define BM 64
#define BN 64
#define BK 32
__global__ __launch_bounds__(256) void lstm_gemm_kernel(
    const float* __restrict__ A1, const float* __restrict__ Wa, int wa_stride,
    const float* __restrict__ A2, const float* __restrict__ Wb, int wb_stride,
    const float* __restrict__ base, float* __restrict__ gates, int B_) {
    __shared__ float As[BM][BK + 1];
    __shared__ float Bs[BN][BK + 1];
    int b0 = blockIdx.y * BM;
    int j0 = blockIdx.x * BN;
    int tid = threadIdx.x;
    int tx = tid & 15, ty = tid >> 4;
    float acc[4][4] = {};
    int nphase = A2 ? 2 : 1;
    for (int phase = 0; phase < nphase; phase++) {
        const float* A = phase ? A2 : A1;
        const float* W = phase ? Wb : Wa;
        int ws = phase ? wb_stride : wa_stride;
        for (int k0 = 0; k0 < 128; k0 += BK) {
            __syncthreads();
            for (int i = tid; i < BM * BK; i += 256) {
                int r = i >> 5, cc = i & 31;
                int bb = b0 + r;
                As[r][cc] = (bb < B_) ? A[(size_t)bb * D + k0 + cc] : 0.f;
            }
            for (int i = tid; i < BN * BK; i += 256) {
                int r = i >> 5, cc = i & 31;
                Bs[r][cc] = W[(size_t)(j0 + r) * ws + k0 + cc];
            }
            __syncthreads();
#pragma unroll
            for (int kk = 0; kk < BK; kk++) {
                float av[4], bv[4];
#pragma unroll
                for (int i = 0; i < 4; i++) av[i] = As[ty * 4 + i][kk];
#pragma unroll
                for (int j = 0; j < 4; j++) bv[j] = Bs[tx * 4 + j][kk];
#pragma unroll
                for (int i = 0; i < 4; i++)
#pragma unroll
                    for (int j = 0; j < 4; j++) acc[i][j] += av[i] * bv[j];
            }
        }
    }
    for (int i = 0; i < 4; i++) {
        int bb = b0 + ty * 4 + i;
        if (bb >= B_) continue;
        for (int j = 0; j < 4; j++) {
            int jj = j0 + tx * 4 + j;
            gates[(size_t)bb * 512 + jj] = acc[i][j] + base[jj];
        }
    }
}

// ---------------------------------------------------------------------------
// K5: elementwise LSTM state update from gates
// ---------------------------------------------------------------------------
__global__ void lstm_elem_kernel(const float* __restrict__ gates,
                                 const float* __restrict__ c_prev, int c_bcast,
                                 float* __restrict__ c_out,
                                 float* __restrict__ h_out, int B_) {
    int t = blockIdx.x * 256 + threadIdx.x;
    if (t >= B_ * D) return;
    int b = t >> 7, d = t & (D - 1);
    const float* g = gates + (size_t)b * 512;
    float ig = 1.f / (1.f + __expf(-g[d]));
    float fg = 1.f / (1.f + __expf(-g[128 + d]));
    float gg = tanhf(g[256 + d]);
    float og = 1.f / (1.f + __expf(-g[384 + d]));
    float cp = c_bcast ? c_prev[d] : c_prev[t];
    float c = fg * cp + ig * gg;
    c_out[t] = c;
    h_out[t] = og * tanhf(c);
}

// ---------------------------------------------------------------------------
// K6: per-graph attention, single pass over x with online softmax.
// block = 1 graph, 256 threads. Tile of 64 nodes staged in LDS.
// prod[n] = <query, x[n]>;  out = sum(exp(prod-m)*x) / (sum(exp(prod-m))+EPS)
// ---------------------------------------------------------------------------
__global__ __launch_bounds__(256) void attn_kernel(
    const float* __restrict__ x, const float* __restrict__ q_src, int q_bcast,
    const int* __restrict__ row_ptr, float* __restrict__ out,
    float* __restrict__ final_out) {
    int b = blockIdx.x;
    int tid = threadIdx.x;
    __shared__ float q_s[D];
    __shared__ float xs[TILE][D];   // 32 KB
    __shared__ float w_s[TILE];     // prod, then exp weights
    __shared__ float red_s[256];

    const float* qp = q_bcast ? q_src : q_src + (size_t)b * D;
    if (tid < D) q_s[tid] = qp[tid];

    int s = row_ptr[b], e = row_ptr[b + 1];
    float m = -1e30f, l = 0.f, accr = 0.f;
    int d = tid & (D - 1);
    int par = tid >> 7;  // waves 0,1 -> even nodes; waves 2,3 -> odd nodes

    for (int t0 = s; t0 < e; t0 += TILE) {
        int nt = min(TILE, e - t0);
        __syncthreads();  // protect xs/w_s reuse from previous iteration
        // stage tile (coalesced float4)
        const float4* xg = (const float4*)(x + (size_t)t0 * D);
        int nw = nt * (D / 4);
        for (int i = tid; i < nw; i += 256) ((float4*)xs)[i] = xg[i];
        __syncthreads();
        // prod: 4 threads per node, 32 dims each, lane-staggered b128 reads
        int n = tid >> 2, qd = tid & 3;
        float partial = 0.f;
        if (n < nt) {
            const float4* xr = (const float4*)xs;
            const float4* q4 = (const float4*)q_s;
#pragma unroll
            for (int j = 0; j < 8; j++) {
                int jj = (j + n) & 7;
                float4 xv = xr[n * 32 + qd * 8 + jj];
                float4 qv = q4[qd * 8 + jj];
                partial += xv.x * qv.x + xv.y * qv.y + xv.z * qv.z + xv.w * qv.w;
            }
        }
        partial += __shfl_xor(partial, 1);
        partial += __shfl_xor(partial, 2);
        if (qd == 0 && n < nt) w_s[n] = partial;
        __syncthreads();
        // block-uniform tile max (broadcast reads, redundant per thread)
        float tmax = -1e30f;
        for (int t = 0; t < nt; t++) tmax = fmaxf(tmax, w_s[t]);
        float m_new = fmaxf(m, tmax);
        float r = __expf(m - m_new);  // first tile: exp(-1e30) == 0
        __syncthreads();              // everyone done reading prod values
        if (tid < nt) w_s[tid] = __expf(w_s[tid] - m_new);
        __syncthreads();
        float tsum = 0.f;
        for (int t = 0; t < nt; t++) tsum += w_s[t];
        l = l * r + tsum;
        // accumulate: thread owns dim d, node parity par (2-way LDS = free)
        float a = 0.f;
        for (int t = par; t < nt; t += 2) a += w_s[t] * xs[t][d];
        accr = accr * r + a;
        m = m_new;
    }
    __syncthreads();
    red_s[tid] = accr;
    __syncthreads();
    if (tid < D) {
        float o = (red_s[tid] + red_s[tid + D]) / (l + EPS);
        if (out) out[(size_t)b * D + tid] = o;
        if (final_out) {
            final_out[(size_t)b * 2 * D + tid] = q_s[tid];
            final_out[(size_t)b * 2 * D + D + tid] = o;
        }
    }
}

// ---------------------------------------------------------------------------
extern "C" void kernel_launch(void* const* d_in, const int* in_sizes, int n_in,
                              void* d_out, int out_size, void* d_ws,
                              size_t ws_size, hipStream_t stream) {
    const float* x    = (const float*)d_in[0];
    const float* w_ih = (const float*)d_in[1];
    const float* w_hh = (const float*)d_in[2];
    const float* b_ih = (const float*)d_in[3];
    const float* b_hh = (const float*)d_in[4];
    const int*   n2g  = (const int*)d_in[5];

    int N_ = in_sizes[0] / D;     // 1,000,000
    int B_ = out_size / (2 * D);  // 10,000

    // workspace carve (256B aligned)
    char* wsb = (char*)d_ws;
    size_t off = 0;
    auto carve = [&](size_t bytes) {
        void* p = wsb + off;
        off = (off + bytes + 255) & ~(size_t)255;
        return p;
    };
    int*   row_ptr = (int*)carve((size_t)(B_ + 1) * 4);
    float* b_sum   = (float*)carve(512 * 4);
    float* c1      = (float*)carve(D * 4);
    float* h1      = (float*)carve(D * 4);
    float* const2  = (float*)carve(512 * 4);
    float* W1      = (float*)carve((size_t)512 * D * 4);
    float* hbuf    = (float*)carve((size_t)B_ * D * 4);
    float* cbuf    = (float*)carve((size_t)B_ * D * 4);
    float* outbuf  = (float*)carve((size_t)B_ * D * 4);
    float* gates   = (float*)carve((size_t)B_ * 512 * 4);
    (void)ws_size;

    const float* W2 = w_ih + D;  // rows of w_ih, column offset 128, stride 256

    // setup
    rowptr_kernel<<<(B_ + 1 + 255) / 256, 256, 0, stream>>>(n2g, N_, B_, row_ptr);
    init_consts_kernel<<<1, 512, 0, stream>>>(b_ih, b_hh, b_sum, c1, h1);
    init_w1_kernel<<<512, 128, 0, stream>>>(w_ih, w_hh, b_sum, h1, W1, const2);

    dim3 ggrid(512 / BN, (B_ + BM - 1) / BM);
    int  egrid = (B_ * D + 255) / 256;

    // step 1: query = h1 (broadcast) -> out1
    attn_kernel<<<B_, 256, 0, stream>>>(x, h1, 1, row_ptr, outbuf, nullptr);
    // step 2: gates = const2 + out1 @ W2^T ; c_prev = c1 (broadcast)
    lstm_gemm_kernel<<<ggrid, 256, 0, stream>>>(outbuf, W2, 256, nullptr,
                                                nullptr, 0, const2, gates, B_);
    lstm_elem_kernel<<<egrid, 256, 0, stream>>>(gates, c1, 1, cbuf, hbuf, B_);
    attn_kernel<<<B_, 256, 0, stream>>>(x, hbuf, 0, row_ptr, outbuf, nullptr);
    // step 3: gates = b_sum + h2 @ W1^T + out2 @ W2^T
    lstm_gemm_kernel<<<ggrid, 256, 0, stream>>>(hbuf, W1, 128, outbuf, W2, 256,
                                                b_sum, gates, B_);
    lstm_elem_kernel<<<egrid, 256, 0, stream>>>(gates, cbuf, 0, cbuf, hbuf, B_);
    // step 3 attention writes final q_star = [h3, out3] directly to d_out
    attn_kernel<<<B_, 256, 0, stream>>>(x, hbuf, 0, row_ptr, nullptr,
                                        (float*)d_out);
}